// Round 1
// baseline (943.701 us; speedup 1.0000x reference)
//
#include <hip/hip_runtime.h>
#include <math.h>

#define N_NODES 100000
#define N_EDGES 1600000
#define F_IN    500
#define HIDDEN  64
#define N_CLASS 40

// ---------- small utility kernels ----------
__global__ void k_zero_int(int* p, int n) {
    int i = blockIdx.x * blockDim.x + threadIdx.x;
    if (i < n) p[i] = 0;
}

__global__ void k_hist(const int* __restrict__ dst, int* __restrict__ cnt, int e) {
    int i = blockIdx.x * blockDim.x + threadIdx.x;
    if (i < e) atomicAdd(&cnt[dst[i]], 1);
}

__global__ void k_dinv(const int* __restrict__ cnt, float* __restrict__ dinv, int n) {
    int i = blockIdx.x * blockDim.x + threadIdx.x;
    if (i < n) dinv[i] = rsqrtf((float)(cnt[i] + 1));  // +1 = self loop; deg >= 1 always
}

// ---------- exclusive scan (3-kernel) over cnt[0..N-1] -> row_ptr[0..N] ----------
__global__ void k_scan1(const int* __restrict__ cnt, int* __restrict__ rp,
                        int* __restrict__ part, int n /*N+1*/, int ncnt /*N*/) {
    __shared__ int s[1024];
    int t = threadIdx.x;
    int i = blockIdx.x * 1024 + t;
    int v = (i < ncnt) ? cnt[i] : 0;
    s[t] = v;
    __syncthreads();
    for (int off = 1; off < 1024; off <<= 1) {
        int a = (t >= off) ? s[t - off] : 0;
        __syncthreads();
        s[t] += a;
        __syncthreads();
    }
    if (i < n) rp[i] = s[t] - v;          // exclusive
    if (t == 1023) part[blockIdx.x] = s[1023];
}

__global__ void k_scan2(int* p, int P) {
    __shared__ int s[128];
    int t = threadIdx.x;
    int v = (t < P) ? p[t] : 0;
    s[t] = v;
    __syncthreads();
    for (int off = 1; off < 128; off <<= 1) {
        int a = (t >= off) ? s[t - off] : 0;
        __syncthreads();
        s[t] += a;
        __syncthreads();
    }
    if (t < P) p[t] = s[t] - v;           // exclusive
}

__global__ void k_scan3(int* __restrict__ rp, const int* __restrict__ part, int n) {
    int i = blockIdx.x * 1024 + threadIdx.x;
    if (i < n) rp[i] += part[blockIdx.x];
}

__global__ void k_copy_int(const int* __restrict__ a, int* __restrict__ b, int n) {
    int i = blockIdx.x * blockDim.x + threadIdx.x;
    if (i < n) b[i] = a[i];
}

__global__ void k_fill(const int* __restrict__ src, const int* __restrict__ dst,
                       int* __restrict__ cur, int* __restrict__ col, int e) {
    int i = blockIdx.x * blockDim.x + threadIdx.x;
    if (i < e) {
        int d = dst[i];
        int pos = atomicAdd(&cur[d], 1);
        col[pos] = src[i];
    }
}

// ---------- GEMM1: h[N,64] = x[N,500] @ W[500,64], fp32 register-tiled ----------
// block = 256 threads computes a 64-row x 64-col tile; each thread: 16 rows x 1 col.
__launch_bounds__(256)
__global__ void k_gemm1(const float* __restrict__ x, const float* __restrict__ w,
                        float* __restrict__ h, int n) {
    __shared__ float xs[64][36];   // KT=32 + pad to 36 floats (144B, keeps 16B align for b128)
    __shared__ float ws[32][64];
    const int tid = threadIdx.x;
    const int col = tid & 63;
    const int rq  = tid >> 6;      // 0..3 -> rows rq*16 .. rq*16+15
    const int row0 = blockIdx.x * 64;

    float acc[16];
#pragma unroll
    for (int r = 0; r < 16; ++r) acc[r] = 0.f;

    for (int k0 = 0; k0 < F_IN; k0 += 32) {
        const int kt  = min(32, F_IN - k0);   // 32 or 20 (tail)
        const int ktq = kt >> 2;              // 8 or 5
        // stage x tile (row stride 500 floats = 2000B is 16B-multiple -> float4 ok)
        for (int idx = tid; idx < 64 * ktq; idx += 256) {
            int r = idx / ktq, q = idx - r * ktq;
            float4 v = make_float4(0.f, 0.f, 0.f, 0.f);
            int gr = row0 + r;
            if (gr < n) v = *(const float4*)&x[gr * F_IN + k0 + 4 * q];
            *(float4*)&xs[r][4 * q] = v;
        }
        // stage W tile
        for (int idx = tid; idx < kt * 16; idx += 256) {
            int kk = idx >> 4, q = idx & 15;
            *(float4*)&ws[kk][4 * q] = *(const float4*)&w[(k0 + kk) * HIDDEN + 4 * q];
        }
        __syncthreads();
        for (int kk = 0; kk < kt; kk += 4) {
            float w0 = ws[kk][col], w1 = ws[kk + 1][col];
            float w2 = ws[kk + 2][col], w3 = ws[kk + 3][col];
#pragma unroll
            for (int r = 0; r < 16; ++r) {
                float4 xv = *(const float4*)&xs[rq * 16 + r][kk];  // wave-broadcast b128
                acc[r] = fmaf(xv.x, w0, acc[r]);
                acc[r] = fmaf(xv.y, w1, acc[r]);
                acc[r] = fmaf(xv.z, w2, acc[r]);
                acc[r] = fmaf(xv.w, w3, acc[r]);
            }
        }
        __syncthreads();
    }
#pragma unroll
    for (int r = 0; r < 16; ++r) {
        int gr = row0 + rq * 16 + r;
        if (gr < n) h[gr * HIDDEN + col] = acc[r];
    }
}

// ---------- aggregation: out[i] = dinv[i]*sum_e dinv[s]*h[s] + dinv[i]^2*h[i] + b ----------
template <int F, bool RELU>
__global__ void k_agg(const float* __restrict__ h, const int* __restrict__ rp,
                      const int* __restrict__ col, const float* __restrict__ dinv,
                      const float* __restrict__ bias, float* __restrict__ out, int n) {
    int wid  = (blockIdx.x * blockDim.x + threadIdx.x) >> 6;  // one wave per node
    int lane = threadIdx.x & 63;
    if (wid >= n) return;
    int beg = rp[wid], end = rp[wid + 1];
    float acc = 0.f;
    for (int e = beg; e < end; ++e) {
        int s   = col[e];
        float w = dinv[s];
        float hv = (lane < F) ? h[s * F + lane] : 0.f;
        acc += w * hv;
    }
    if (lane < F) {
        float di    = dinv[wid];
        float selfv = h[wid * F + lane];
        float r = di * acc + di * di * selfv + bias[lane];
        if (RELU) r = fmaxf(r, 0.f);
        out[wid * F + lane] = r;
    }
}

// ---------- GEMM2: out[N,40] = a[N,64] @ W2[64,40] ----------
__launch_bounds__(256)
__global__ void k_gemm2(const float* __restrict__ a, const float* __restrict__ w,
                        float* __restrict__ out, int n) {
    __shared__ float ws[HIDDEN * N_CLASS];
    for (int idx = threadIdx.x; idx < HIDDEN * N_CLASS; idx += 256) ws[idx] = w[idx];
    __syncthreads();
    int idx = blockIdx.x * 256 + threadIdx.x;
    if (idx >= n * N_CLASS) return;
    int i = idx / N_CLASS, j = idx - i * N_CLASS;
    float s = 0.f;
#pragma unroll
    for (int k = 0; k < HIDDEN; k += 4) {
        float4 xv = *(const float4*)&a[i * HIDDEN + k];
        s = fmaf(xv.x, ws[k * N_CLASS + j], s);
        s = fmaf(xv.y, ws[(k + 1) * N_CLASS + j], s);
        s = fmaf(xv.z, ws[(k + 2) * N_CLASS + j], s);
        s = fmaf(xv.w, ws[(k + 3) * N_CLASS + j], s);
    }
    out[idx] = s;
}

// ---------- log_softmax over 40 classes, in place ----------
__global__ void k_lsm(float* __restrict__ out, int n) {
    int wid  = (blockIdx.x * blockDim.x + threadIdx.x) >> 6;
    int lane = threadIdx.x & 63;
    if (wid >= n) return;
    float v = (lane < N_CLASS) ? out[wid * N_CLASS + lane] : -INFINITY;
    float m = v;
    for (int off = 32; off; off >>= 1) m = fmaxf(m, __shfl_xor(m, off));
    float ex = (lane < N_CLASS) ? expf(v - m) : 0.f;
    float s = ex;
    for (int off = 32; off; off >>= 1) s += __shfl_xor(s, off);
    if (lane < N_CLASS) out[wid * N_CLASS + lane] = v - m - logf(s);
}

extern "C" void kernel_launch(void* const* d_in, const int* in_sizes, int n_in,
                              void* d_out, int out_size, void* d_ws, size_t ws_size,
                              hipStream_t stream) {
    const float* x   = (const float*)d_in[0];
    const float* W1  = (const float*)d_in[1];
    const float* b1  = (const float*)d_in[2];
    const float* W2  = (const float*)d_in[3];
    const float* b2  = (const float*)d_in[4];
    const int*   ei  = (const int*)d_in[5];
    const int*   src = ei;
    const int*   dst = ei + N_EDGES;
    float*       out = (float*)d_out;

    // workspace carve-up (~59 MB total)
    char*  ws  = (char*)d_ws;
    size_t off = 0;
    auto alloc = [&](size_t bytes) -> void* {
        void* p = ws + off;
        off += (bytes + 255) & ~(size_t)255;
        return p;
    };
    int*   cnt  = (int*)alloc((size_t)N_NODES * 4);
    int*   rp   = (int*)alloc((size_t)(N_NODES + 1) * 4);
    int*   cur  = (int*)alloc((size_t)N_NODES * 4);
    int*   part = (int*)alloc(128 * 4);
    int*   col  = (int*)alloc((size_t)N_EDGES * 4);
    float* dinv = (float*)alloc((size_t)N_NODES * 4);
    float* h1   = (float*)alloc((size_t)N_NODES * HIDDEN * 4);
    float* h1a  = (float*)alloc((size_t)N_NODES * HIDDEN * 4);
    float* h2   = h1;  // reuse: h1 dead after agg1

    const int NB256_N = (N_NODES + 255) / 256;
    const int NB256_E = (N_EDGES + 255) / 256;
    const int NP1     = N_NODES + 1;
    const int NBLK    = (NP1 + 1023) / 1024;  // 98

    // CSR build (by dst) + degree normalization
    k_zero_int<<<NB256_N, 256, 0, stream>>>(cnt, N_NODES);
    k_hist<<<NB256_E, 256, 0, stream>>>(dst, cnt, N_EDGES);
    k_dinv<<<NB256_N, 256, 0, stream>>>(cnt, dinv, N_NODES);
    k_scan1<<<NBLK, 1024, 0, stream>>>(cnt, rp, part, NP1, N_NODES);
    k_scan2<<<1, 128, 0, stream>>>(part, NBLK);
    k_scan3<<<NBLK, 1024, 0, stream>>>(rp, part, NP1);
    k_copy_int<<<NB256_N, 256, 0, stream>>>(rp, cur, N_NODES);
    k_fill<<<NB256_E, 256, 0, stream>>>(src, dst, cur, col, N_EDGES);

    // layer 1
    k_gemm1<<<(N_NODES + 63) / 64, 256, 0, stream>>>(x, W1, h1, N_NODES);
    k_agg<HIDDEN, true><<<(N_NODES + 3) / 4, 256, 0, stream>>>(h1, rp, col, dinv, b1, h1a, N_NODES);

    // layer 2
    k_gemm2<<<(N_NODES * N_CLASS + 255) / 256, 256, 0, stream>>>(h1a, W2, h2, N_NODES);
    k_agg<N_CLASS, false><<<(N_NODES + 3) / 4, 256, 0, stream>>>(h2, rp, col, dinv, b2, out, N_NODES);

    // log_softmax in place
    k_lsm<<<(N_NODES + 3) / 4, 256, 0, stream>>>(out, N_NODES);
}

// Round 2
// 773.943 us; speedup vs baseline: 1.2193x; 1.2193x over previous
//
#include <hip/hip_runtime.h>
#include <math.h>

#define N_NODES 100000
#define N_EDGES 1600000
#define F_IN    500
#define HIDDEN  64
#define N_CLASS 40
#define KPAD    512

typedef __attribute__((ext_vector_type(4))) float f32x4;
typedef __attribute__((ext_vector_type(8))) __bf16 bf16x8;

__device__ __forceinline__ unsigned short f2bf(float f) {
    unsigned int u = __float_as_uint(f);
    u = (u + 0x7FFF + ((u >> 16) & 1)) >> 16;   // RNE
    return (unsigned short)u;
}

// ---------- small utility kernels ----------
__global__ void k_zero_int(int* p, int n) {
    int i = blockIdx.x * blockDim.x + threadIdx.x;
    if (i < n) p[i] = 0;
}

__global__ void k_hist(const int* __restrict__ dst, int* __restrict__ cnt, int e) {
    int i = blockIdx.x * blockDim.x + threadIdx.x;
    if (i < e) atomicAdd(&cnt[dst[i]], 1);
}

__global__ void k_dinv(const int* __restrict__ cnt, float* __restrict__ dinv, int n) {
    int i = blockIdx.x * blockDim.x + threadIdx.x;
    if (i < n) dinv[i] = rsqrtf((float)(cnt[i] + 1));  // +1 = self loop
}

// W1t[n][k] = bf16(W1[k][n]), k zero-padded to 512
__global__ void k_prep_w1t(const float* __restrict__ w1, unsigned short* __restrict__ w1t) {
    int idx = blockIdx.x * blockDim.x + threadIdx.x;   // 64*512
    if (idx >= HIDDEN * KPAD) return;
    int n = idx >> 9, k = idx & (KPAD - 1);
    float v = (k < F_IN) ? w1[k * HIDDEN + n] : 0.f;
    w1t[idx] = f2bf(v);
}

// ---------- exclusive scan (3-kernel) ----------
__global__ void k_scan1(const int* __restrict__ cnt, int* __restrict__ rp,
                        int* __restrict__ part, int n, int ncnt) {
    __shared__ int s[1024];
    int t = threadIdx.x;
    int i = blockIdx.x * 1024 + t;
    int v = (i < ncnt) ? cnt[i] : 0;
    s[t] = v;
    __syncthreads();
    for (int off = 1; off < 1024; off <<= 1) {
        int a = (t >= off) ? s[t - off] : 0;
        __syncthreads();
        s[t] += a;
        __syncthreads();
    }
    if (i < n) rp[i] = s[t] - v;
    if (t == 1023) part[blockIdx.x] = s[1023];
}

__global__ void k_scan2(int* p, int P) {
    __shared__ int s[128];
    int t = threadIdx.x;
    int v = (t < P) ? p[t] : 0;
    s[t] = v;
    __syncthreads();
    for (int off = 1; off < 128; off <<= 1) {
        int a = (t >= off) ? s[t - off] : 0;
        __syncthreads();
        s[t] += a;
        __syncthreads();
    }
    if (t < P) p[t] = s[t] - v;
}

__global__ void k_scan3(int* __restrict__ rp, const int* __restrict__ part, int n) {
    int i = blockIdx.x * 1024 + threadIdx.x;
    if (i < n) rp[i] += part[blockIdx.x];
}

__global__ void k_copy_int(const int* __restrict__ a, int* __restrict__ b, int n) {
    int i = blockIdx.x * blockDim.x + threadIdx.x;
    if (i < n) b[i] = a[i];
}

__global__ void k_fill(const int* __restrict__ src, const int* __restrict__ dst,
                       int* __restrict__ cur, int* __restrict__ col, int e) {
    int i = blockIdx.x * blockDim.x + threadIdx.x;
    if (i < e) {
        int d = dst[i];
        int pos = atomicAdd(&cur[d], 1);
        col[pos] = src[i];
    }
}

// ---------- GEMM1: h[N,64] = x[N,500] @ W1[500,64] via bf16 MFMA ----------
// block = 256 (4 waves), block tile = 128 rows. wave tile = 32 rows x 64 cols
// = 2 (rt) x 4 (ct) mfma_16x16x32 accumulators. No LDS: A from global fp32
// (cvt to bf16 in-reg), B from the prepped bf16 W1t[64][512] (L2-resident).
__launch_bounds__(256)
__global__ void k_gemm1(const float* __restrict__ x, const unsigned short* __restrict__ w1t,
                        float* __restrict__ h, int n) {
    const int tid  = threadIdx.x;
    const int wave = tid >> 6;
    const int lane = tid & 63;
    const int quad = lane >> 4;
    const int l16  = lane & 15;
    const int rowb = blockIdx.x * 128 + wave * 32;

    f32x4 acc[2][4];
#pragma unroll
    for (int rt = 0; rt < 2; ++rt)
#pragma unroll
        for (int ct = 0; ct < 4; ++ct) acc[rt][ct] = (f32x4)0.f;

    int  arow[2];
    bool avalid[2];
#pragma unroll
    for (int rt = 0; rt < 2; ++rt) {
        arow[rt]   = rowb + rt * 16 + l16;
        avalid[rt] = arow[rt] < n;
    }

    for (int ks = 0; ks < 16; ++ks) {
        const int k0 = ks * 32;
        // B fragments: 16B direct loads from bf16 W1t (k-major, padded)
        bf16x8 bfrag[4];
#pragma unroll
        for (int ct = 0; ct < 4; ++ct)
            bfrag[ct] = *(const bf16x8*)&w1t[(ct * 16 + l16) * KPAD + k0 + quad * 8];

        union { bf16x8 v; unsigned short u[8]; } af[2];
#pragma unroll
        for (int rt = 0; rt < 2; ++rt) {
            if (avalid[rt]) {
                const float* p = x + (size_t)arow[rt] * F_IN + k0 + quad * 8;
                if (ks < 15) {
                    float4 f0 = *(const float4*)p;
                    float4 f1 = *(const float4*)(p + 4);
                    af[rt].u[0] = f2bf(f0.x); af[rt].u[1] = f2bf(f0.y);
                    af[rt].u[2] = f2bf(f0.z); af[rt].u[3] = f2bf(f0.w);
                    af[rt].u[4] = f2bf(f1.x); af[rt].u[5] = f2bf(f1.y);
                    af[rt].u[6] = f2bf(f1.z); af[rt].u[7] = f2bf(f1.w);
                } else {
#pragma unroll
                    for (int j = 0; j < 8; ++j) {
                        int k = k0 + quad * 8 + j;
                        af[rt].u[j] = (k < F_IN) ? f2bf(p[j]) : (unsigned short)0;
                    }
                }
            } else {
#pragma unroll
                for (int j = 0; j < 8; ++j) af[rt].u[j] = 0;
            }
        }
#pragma unroll
        for (int rt = 0; rt < 2; ++rt)
#pragma unroll
            for (int ct = 0; ct < 4; ++ct)
                acc[rt][ct] = __builtin_amdgcn_mfma_f32_16x16x32_bf16(
                    af[rt].v, bfrag[ct], acc[rt][ct], 0, 0, 0);
    }

    // D layout: row = quad*4 + reg, col = lane&15
#pragma unroll
    for (int rt = 0; rt < 2; ++rt) {
#pragma unroll
        for (int reg = 0; reg < 4; ++reg) {
            int grow = rowb + rt * 16 + quad * 4 + reg;
            if (grow < n) {
#pragma unroll
                for (int ct = 0; ct < 4; ++ct)
                    h[(size_t)grow * HIDDEN + ct * 16 + l16] = acc[rt][ct][reg];
            }
        }
    }
}

// ---------- aggregation ----------
// out[i] = dinv[i]*sum_e dinv[s]*h[s] + dinv[i]^2*h[i] + b  (+ReLU or +log_softmax)
template <int F, bool RELU, bool LSM>
__global__ void k_agg(const float* __restrict__ h, const int* __restrict__ rp,
                      const int* __restrict__ col, const float* __restrict__ dinv,
                      const float* __restrict__ bias, float* __restrict__ out, int n) {
    int wid  = (blockIdx.x * blockDim.x + threadIdx.x) >> 6;  // one wave per node
    int lane = threadIdx.x & 63;
    if (wid >= n) return;
    int beg = rp[wid], end = rp[wid + 1];
    float acc = 0.f;
    int e = beg;
    for (; e + 2 <= end; e += 2) {          // 2-edge unroll -> 2x MLP
        int s0 = col[e], s1 = col[e + 1];
        float w0 = dinv[s0], w1 = dinv[s1];
        float h0 = (lane < F) ? h[(size_t)s0 * F + lane] : 0.f;
        float h1 = (lane < F) ? h[(size_t)s1 * F + lane] : 0.f;
        acc += w0 * h0 + w1 * h1;
    }
    if (e < end) {
        int s0 = col[e];
        float w0 = dinv[s0];
        float h0 = (lane < F) ? h[(size_t)s0 * F + lane] : 0.f;
        acc += w0 * h0;
    }
    float di    = dinv[wid];
    float selfv = (lane < F) ? h[(size_t)wid * F + lane] : 0.f;
    float r = di * acc + di * di * selfv + ((lane < F) ? bias[lane] : 0.f);
    if (RELU) r = fmaxf(r, 0.f);
    if (LSM) {
        float v = (lane < F) ? r : -INFINITY;
        float m = v;
        for (int off = 32; off; off >>= 1) m = fmaxf(m, __shfl_xor(m, off));
        float ex = (lane < F) ? __expf(v - m) : 0.f;
        float s = ex;
        for (int off = 32; off; off >>= 1) s += __shfl_xor(s, off);
        if (lane < F) out[(size_t)wid * F + lane] = v - m - __logf(s);
    } else {
        if (lane < F) out[(size_t)wid * F + lane] = r;
    }
}

// ---------- GEMM2: h2[N,40] = a[N,64] @ W2[64,40] ----------
__launch_bounds__(256)
__global__ void k_gemm2(const float* __restrict__ a, const float* __restrict__ w,
                        float* __restrict__ out, int n) {
    __shared__ float ws[HIDDEN * N_CLASS];
    for (int idx = threadIdx.x; idx < HIDDEN * N_CLASS; idx += 256) ws[idx] = w[idx];
    __syncthreads();
    int idx = blockIdx.x * 256 + threadIdx.x;
    if (idx >= n * N_CLASS) return;
    int i = idx / N_CLASS, j = idx - i * N_CLASS;
    float s = 0.f;
#pragma unroll
    for (int k = 0; k < HIDDEN; k += 4) {
        float4 xv = *(const float4*)&a[(size_t)i * HIDDEN + k];
        s = fmaf(xv.x, ws[k * N_CLASS + j], s);
        s = fmaf(xv.y, ws[(k + 1) * N_CLASS + j], s);
        s = fmaf(xv.z, ws[(k + 2) * N_CLASS + j], s);
        s = fmaf(xv.w, ws[(k + 3) * N_CLASS + j], s);
    }
    out[idx] = s;
}

extern "C" void kernel_launch(void* const* d_in, const int* in_sizes, int n_in,
                              void* d_out, int out_size, void* d_ws, size_t ws_size,
                              hipStream_t stream) {
    const float* x   = (const float*)d_in[0];
    const float* W1  = (const float*)d_in[1];
    const float* b1  = (const float*)d_in[2];
    const float* W2  = (const float*)d_in[3];
    const float* b2  = (const float*)d_in[4];
    const int*   ei  = (const int*)d_in[5];
    const int*   src = ei;
    const int*   dst = ei + N_EDGES;
    float*       out = (float*)d_out;

    char*  ws  = (char*)d_ws;
    size_t off = 0;
    auto alloc = [&](size_t bytes) -> void* {
        void* p = ws + off;
        off += (bytes + 255) & ~(size_t)255;
        return p;
    };
    int*            cnt  = (int*)alloc((size_t)N_NODES * 4);
    int*            rp   = (int*)alloc((size_t)(N_NODES + 1) * 4);
    int*            cur  = (int*)alloc((size_t)N_NODES * 4);
    int*            part = (int*)alloc(128 * 4);
    int*            col  = (int*)alloc((size_t)N_EDGES * 4);
    float*          dinv = (float*)alloc((size_t)N_NODES * 4);
    unsigned short* w1t  = (unsigned short*)alloc((size_t)HIDDEN * KPAD * 2);
    float*          h1   = (float*)alloc((size_t)N_NODES * HIDDEN * 4);
    float*          h1a  = (float*)alloc((size_t)N_NODES * HIDDEN * 4);
    float*          h2   = h1;  // h1 dead after agg1

    const int NB256_N = (N_NODES + 255) / 256;
    const int NB256_E = (N_EDGES + 255) / 256;
    const int NP1     = N_NODES + 1;
    const int NBLK    = (NP1 + 1023) / 1024;

    // CSR build (by dst) + degree normalization + W1^T prep
    k_zero_int<<<NB256_N, 256, 0, stream>>>(cnt, N_NODES);
    k_hist<<<NB256_E, 256, 0, stream>>>(dst, cnt, N_EDGES);
    k_dinv<<<NB256_N, 256, 0, stream>>>(cnt, dinv, N_NODES);
    k_prep_w1t<<<(HIDDEN * KPAD + 255) / 256, 256, 0, stream>>>(W1, w1t);
    k_scan1<<<NBLK, 1024, 0, stream>>>(cnt, rp, part, NP1, N_NODES);
    k_scan2<<<1, 128, 0, stream>>>(part, NBLK);
    k_scan3<<<NBLK, 1024, 0, stream>>>(rp, part, NP1);
    k_copy_int<<<NB256_N, 256, 0, stream>>>(rp, cur, N_NODES);
    k_fill<<<NB256_E, 256, 0, stream>>>(src, dst, cur, col, N_EDGES);

    // layer 1
    k_gemm1<<<(N_NODES + 127) / 128, 256, 0, stream>>>(x, w1t, h1, N_NODES);
    k_agg<HIDDEN, true, false><<<(N_NODES + 3) / 4, 256, 0, stream>>>(h1, rp, col, dinv, b1, h1a, N_NODES);

    // layer 2 (+fused log_softmax in agg epilogue)
    k_gemm2<<<(N_NODES * N_CLASS + 255) / 256, 256, 0, stream>>>(h1a, W2, h2, N_NODES);
    k_agg<N_CLASS, false, true><<<(N_NODES + 3) / 4, 256, 0, stream>>>(h2, rp, col, dinv, b2, out, N_NODES);
}

// Round 3
// 635.290 us; speedup vs baseline: 1.4855x; 1.2183x over previous
//
#include <hip/hip_runtime.h>
#include <math.h>

#define N_NODES 100000
#define N_EDGES 1600000
#define F_IN    500
#define HIDDEN  64
#define N_CLASS 40
#define KPAD    512

#define NB   2048      // dst buckets
#define NPB  49        // nodes per bucket (2048*49 = 100352 >= N)
#define EPB  16384     // edges per block in bhist/bfill
#define CAP  1536      // LDS pair capacity in k_bucket_csr (mean 781, 27 sigma)

typedef __attribute__((ext_vector_type(4))) float f32x4;
typedef __attribute__((ext_vector_type(8))) __bf16 bf16x8;

__device__ __forceinline__ unsigned short f2bf(float f) {
    unsigned int u = __float_as_uint(f);
    u = (u + 0x7FFF + ((u >> 16) & 1)) >> 16;   // RNE
    return (unsigned short)u;
}

// ---------- utility ----------
__global__ void k_zero_int(int* p, int n) {
    int i = blockIdx.x * blockDim.x + threadIdx.x;
    if (i < n) p[i] = 0;
}

// W1t[n][k] = bf16(W1[k][n]), k zero-padded to 512
__global__ void k_prep_w1t(const float* __restrict__ w1, unsigned short* __restrict__ w1t) {
    int idx = blockIdx.x * blockDim.x + threadIdx.x;
    if (idx >= HIDDEN * KPAD) return;
    int n = idx >> 9, k = idx & (KPAD - 1);
    float v = (k < F_IN) ? w1[k * HIDDEN + n] : 0.f;
    w1t[idx] = f2bf(v);
}

// ---------- CSR build: bucketed counting sort ----------
__launch_bounds__(1024)
__global__ void k_bhist(const int* __restrict__ dst, int* __restrict__ bcnt, int e) {
    __shared__ int h[NB];
    for (int i = threadIdx.x; i < NB; i += 1024) h[i] = 0;
    __syncthreads();
    int base = blockIdx.x * EPB;
#pragma unroll
    for (int j = 0; j < 16; ++j) {
        int i = base + j * 1024 + threadIdx.x;
        if (i < e) atomicAdd(&h[dst[i] / NPB], 1);
    }
    __syncthreads();
    for (int i = threadIdx.x; i < NB; i += 1024)
        if (h[i]) atomicAdd(&bcnt[i], h[i]);
}

__launch_bounds__(1024)
__global__ void k_bscan(const int* __restrict__ bcnt, int* __restrict__ bptr,
                        int* __restrict__ bcur) {
    __shared__ int s[1024];
    int t = threadIdx.x;
    int a = bcnt[2 * t], b = bcnt[2 * t + 1];
    int v = a + b;
    s[t] = v;
    __syncthreads();
    for (int off = 1; off < 1024; off <<= 1) {
        int u = (t >= off) ? s[t - off] : 0;
        __syncthreads();
        s[t] += u;
        __syncthreads();
    }
    int excl = s[t] - v;
    bptr[2 * t] = excl;     bptr[2 * t + 1] = excl + a;
    bcur[2 * t] = excl;     bcur[2 * t + 1] = excl + a;
    if (t == 1023) bptr[NB] = s[1023];
}

// per-block LDS histogram + one global reservation per (block,bucket); each
// bucket window is then written by a single CU -> full lines, no cross-XCD
// partial-line write amplification.
__launch_bounds__(1024)
__global__ void k_bfill(const int* __restrict__ src, const int* __restrict__ dst,
                        int* __restrict__ bcur, int2* __restrict__ ebuf, int e) {
    __shared__ int hist[NB];
    __shared__ int base_[NB];
    for (int i = threadIdx.x; i < NB; i += 1024) hist[i] = 0;
    __syncthreads();
    int b0 = blockIdx.x * EPB;
    int s_[16], d_[16];
#pragma unroll
    for (int j = 0; j < 16; ++j) {
        int i = b0 + j * 1024 + threadIdx.x;
        if (i < e) {
            s_[j] = src[i];
            d_[j] = dst[i];
            atomicAdd(&hist[d_[j] / NPB], 1);
        } else d_[j] = -1;
    }
    __syncthreads();
    for (int i = threadIdx.x; i < NB; i += 1024) {
        int hc = hist[i];
        base_[i] = hc ? atomicAdd(&bcur[i], hc) : 0;
        hist[i] = 0;    // reuse as local cursor
    }
    __syncthreads();
#pragma unroll
    for (int j = 0; j < 16; ++j) {
        if (d_[j] >= 0) {
            int bu = d_[j] / NPB;
            int r = atomicAdd(&hist[bu], 1);
            ebuf[base_[bu] + r] = make_int2(s_[j], d_[j]);
        }
    }
}

// one block per bucket: exact per-node CSR (rp, col) + dinv, all from LDS.
__launch_bounds__(256)
__global__ void k_bucket_csr(const int2* __restrict__ ebuf, const int* __restrict__ bptr,
                             int* __restrict__ rp, int* __restrict__ col,
                             float* __restrict__ dinv, int n) {
    int b  = blockIdx.x;
    int lo = b * NPB;
    if (lo >= n) return;
    int hi  = min(lo + NPB, n);
    int eb0 = bptr[b], ec = bptr[b + 1] - eb0;

    __shared__ int2 pairs[CAP];
    __shared__ int  hist[NPB];
    __shared__ int  excl[NPB + 1];
    for (int j = threadIdx.x; j < NPB; j += 256) hist[j] = 0;
    __syncthreads();
    for (int i = threadIdx.x; i < ec; i += 256) {
        int2 p = ebuf[eb0 + i];
        if (i < CAP) pairs[i] = p;
        atomicAdd(&hist[p.y - lo], 1);
    }
    __syncthreads();
    if (threadIdx.x == 0) {
        int acc = 0;
        for (int j = 0; j < NPB; ++j) { excl[j] = acc; acc += hist[j]; }
        excl[NPB] = acc;
    }
    __syncthreads();
    for (int j = threadIdx.x; j < hi - lo; j += 256) {
        rp[lo + j]   = eb0 + excl[j];
        dinv[lo + j] = rsqrtf((float)(hist[j] + 1));   // +1 self loop
    }
    if (hi == n && threadIdx.x == 0) rp[n] = eb0 + ec;
    __syncthreads();                  // all reads of hist done before reuse
    for (int j = threadIdx.x; j < NPB; j += 256) hist[j] = 0;  // reuse as cursor
    __syncthreads();
    for (int i = threadIdx.x; i < ec; i += 256) {
        int2 p  = (i < CAP) ? pairs[i] : ebuf[eb0 + i];
        int  li = p.y - lo;
        int  r  = atomicAdd(&hist[li], 1);
        col[eb0 + excl[li] + r] = p.x;
    }
}

// ---------- GEMM1: h[N,64] = x[N,500] @ W1 via bf16 MFMA (no LDS) ----------
__launch_bounds__(256)
__global__ void k_gemm1(const float* __restrict__ x, const unsigned short* __restrict__ w1t,
                        float* __restrict__ h, int n) {
    const int tid  = threadIdx.x;
    const int wave = tid >> 6;
    const int lane = tid & 63;
    const int quad = lane >> 4;
    const int l16  = lane & 15;
    const int rowb = blockIdx.x * 128 + wave * 32;

    f32x4 acc[2][4];
#pragma unroll
    for (int rt = 0; rt < 2; ++rt)
#pragma unroll
        for (int ct = 0; ct < 4; ++ct) acc[rt][ct] = (f32x4)0.f;

    int  arow[2];
    bool avalid[2];
#pragma unroll
    for (int rt = 0; rt < 2; ++rt) {
        arow[rt]   = rowb + rt * 16 + l16;
        avalid[rt] = arow[rt] < n;
    }

    for (int ks = 0; ks < 16; ++ks) {
        const int k0 = ks * 32;
        bf16x8 bfrag[4];
#pragma unroll
        for (int ct = 0; ct < 4; ++ct)
            bfrag[ct] = *(const bf16x8*)&w1t[(ct * 16 + l16) * KPAD + k0 + quad * 8];

        union { bf16x8 v; unsigned short u[8]; } af[2];
#pragma unroll
        for (int rt = 0; rt < 2; ++rt) {
            if (avalid[rt]) {
                const float* p = x + (size_t)arow[rt] * F_IN + k0 + quad * 8;
                if (ks < 15) {
                    float4 f0 = *(const float4*)p;
                    float4 f1 = *(const float4*)(p + 4);
                    af[rt].u[0] = f2bf(f0.x); af[rt].u[1] = f2bf(f0.y);
                    af[rt].u[2] = f2bf(f0.z); af[rt].u[3] = f2bf(f0.w);
                    af[rt].u[4] = f2bf(f1.x); af[rt].u[5] = f2bf(f1.y);
                    af[rt].u[6] = f2bf(f1.z); af[rt].u[7] = f2bf(f1.w);
                } else {
#pragma unroll
                    for (int j = 0; j < 8; ++j) {
                        int k = k0 + quad * 8 + j;
                        af[rt].u[j] = (k < F_IN) ? f2bf(p[j]) : (unsigned short)0;
                    }
                }
            } else {
#pragma unroll
                for (int j = 0; j < 8; ++j) af[rt].u[j] = 0;
            }
        }
#pragma unroll
        for (int rt = 0; rt < 2; ++rt)
#pragma unroll
            for (int ct = 0; ct < 4; ++ct)
                acc[rt][ct] = __builtin_amdgcn_mfma_f32_16x16x32_bf16(
                    af[rt].v, bfrag[ct], acc[rt][ct], 0, 0, 0);
    }

#pragma unroll
    for (int rt = 0; rt < 2; ++rt) {
#pragma unroll
        for (int reg = 0; reg < 4; ++reg) {
            int grow = rowb + rt * 16 + quad * 4 + reg;
            if (grow < n) {
#pragma unroll
                for (int ct = 0; ct < 4; ++ct)
                    h[(size_t)grow * HIDDEN + ct * 16 + l16] = acc[rt][ct][reg];
            }
        }
    }
}

// ---------- aggregation (+optional ReLU / fused log_softmax) ----------
template <int F, bool RELU, bool LSM>
__global__ void k_agg(const float* __restrict__ h, const int* __restrict__ rp,
                      const int* __restrict__ col, const float* __restrict__ dinv,
                      const float* __restrict__ bias, float* __restrict__ out, int n) {
    int wid  = (blockIdx.x * blockDim.x + threadIdx.x) >> 6;
    int lane = threadIdx.x & 63;
    if (wid >= n) return;
    int beg = rp[wid], end = rp[wid + 1];
    float acc = 0.f;
    int e = beg;
    for (; e + 2 <= end; e += 2) {
        int s0 = col[e], s1 = col[e + 1];
        float w0 = dinv[s0], w1 = dinv[s1];
        float h0 = (lane < F) ? h[(size_t)s0 * F + lane] : 0.f;
        float h1 = (lane < F) ? h[(size_t)s1 * F + lane] : 0.f;
        acc += w0 * h0 + w1 * h1;
    }
    if (e < end) {
        int s0 = col[e];
        float w0 = dinv[s0];
        float h0 = (lane < F) ? h[(size_t)s0 * F + lane] : 0.f;
        acc += w0 * h0;
    }
    float di    = dinv[wid];
    float selfv = (lane < F) ? h[(size_t)wid * F + lane] : 0.f;
    float r = di * acc + di * di * selfv + ((lane < F) ? bias[lane] : 0.f);
    if (RELU) r = fmaxf(r, 0.f);
    if (LSM) {
        float v = (lane < F) ? r : -INFINITY;
        float m = v;
        for (int off = 32; off; off >>= 1) m = fmaxf(m, __shfl_xor(m, off));
        float ex = (lane < F) ? __expf(v - m) : 0.f;
        float s = ex;
        for (int off = 32; off; off >>= 1) s += __shfl_xor(s, off);
        if (lane < F) out[(size_t)wid * F + lane] = v - m - __logf(s);
    } else {
        if (lane < F) out[(size_t)wid * F + lane] = r;
    }
}

// ---------- GEMM2: h2[N,40] = a[N,64] @ W2[64,40] ----------
__launch_bounds__(256)
__global__ void k_gemm2(const float* __restrict__ a, const float* __restrict__ w,
                        float* __restrict__ out, int n) {
    __shared__ float ws[HIDDEN * N_CLASS];
    for (int idx = threadIdx.x; idx < HIDDEN * N_CLASS; idx += 256) ws[idx] = w[idx];
    __syncthreads();
    int idx = blockIdx.x * 256 + threadIdx.x;
    if (idx >= n * N_CLASS) return;
    int i = idx / N_CLASS, j = idx - i * N_CLASS;
    float s = 0.f;
#pragma unroll
    for (int k = 0; k < HIDDEN; k += 4) {
        float4 xv = *(const float4*)&a[(size_t)i * HIDDEN + k];
        s = fmaf(xv.x, ws[k * N_CLASS + j], s);
        s = fmaf(xv.y, ws[(k + 1) * N_CLASS + j], s);
        s = fmaf(xv.z, ws[(k + 2) * N_CLASS + j], s);
        s = fmaf(xv.w, ws[(k + 3) * N_CLASS + j], s);
    }
    out[idx] = s;
}

extern "C" void kernel_launch(void* const* d_in, const int* in_sizes, int n_in,
                              void* d_out, int out_size, void* d_ws, size_t ws_size,
                              hipStream_t stream) {
    const float* x   = (const float*)d_in[0];
    const float* W1  = (const float*)d_in[1];
    const float* b1  = (const float*)d_in[2];
    const float* W2  = (const float*)d_in[3];
    const float* b2  = (const float*)d_in[4];
    const int*   ei  = (const int*)d_in[5];
    const int*   src = ei;
    const int*   dst = ei + N_EDGES;
    float*       out = (float*)d_out;

    char*  ws  = (char*)d_ws;
    size_t off = 0;
    auto alloc = [&](size_t bytes) -> void* {
        void* p = ws + off;
        off += (bytes + 255) & ~(size_t)255;
        return p;
    };
    int*            bcnt = (int*)alloc((size_t)NB * 4);
    int*            bptr = (int*)alloc((size_t)(NB + 1) * 4);
    int*            bcur = (int*)alloc((size_t)NB * 4);
    int*            rp   = (int*)alloc((size_t)(N_NODES + 1) * 4);
    int*            col  = (int*)alloc((size_t)N_EDGES * 4);
    float*          dinv = (float*)alloc((size_t)N_NODES * 4);
    unsigned short* w1t  = (unsigned short*)alloc((size_t)HIDDEN * KPAD * 2);
    float*          h1   = (float*)alloc((size_t)N_NODES * HIDDEN * 4);
    float*          h1a  = (float*)alloc((size_t)N_NODES * HIDDEN * 4);
    int2*           ebuf = (int2*)h1a;   // alias: ebuf (12.8MB) dead before agg1 writes h1a
    float*          h2   = h1;           // h1 dead after agg1

    const int NBH = (N_EDGES + EPB - 1) / EPB;   // 98

    // CSR build (bucketed counting sort) + W1^T prep
    k_zero_int<<<(NB + 255) / 256, 256, 0, stream>>>(bcnt, NB);
    k_prep_w1t<<<(HIDDEN * KPAD + 255) / 256, 256, 0, stream>>>(W1, w1t);
    k_bhist<<<NBH, 1024, 0, stream>>>(dst, bcnt, N_EDGES);
    k_bscan<<<1, 1024, 0, stream>>>(bcnt, bptr, bcur);
    k_bfill<<<NBH, 1024, 0, stream>>>(src, dst, bcur, ebuf, N_EDGES);
    k_bucket_csr<<<NB, 256, 0, stream>>>(ebuf, bptr, rp, col, dinv, N_NODES);

    // layer 1
    k_gemm1<<<(N_NODES + 127) / 128, 256, 0, stream>>>(x, w1t, h1, N_NODES);
    k_agg<HIDDEN, true, false><<<(N_NODES + 3) / 4, 256, 0, stream>>>(h1, rp, col, dinv, b1, h1a, N_NODES);

    // layer 2 (+fused log_softmax)
    k_gemm2<<<(N_NODES * N_CLASS + 255) / 256, 256, 0, stream>>>(h1a, W2, h2, N_NODES);
    k_agg<N_CLASS, false, true><<<(N_NODES + 3) / 4, 256, 0, stream>>>(h2, rp, col, dinv, b2, out, N_NODES);
}

// Round 4
// 565.795 us; speedup vs baseline: 1.6679x; 1.1228x over previous
//
#include <hip/hip_runtime.h>
#include <math.h>

#define N_NODES 100000
#define N_EDGES 1600000
#define F_IN    500
#define HIDDEN  64
#define N_CLASS 40
#define KPAD    512

#define NB   2048      // dst buckets
#define NPB  49        // nodes per bucket (2048*49 = 100352 >= N)
#define EPB  16384     // edges per block in bhist/bfill
#define CAP  1536      // LDS pair capacity in k_bucket_csr (mean 781, 27 sigma)

typedef __attribute__((ext_vector_type(4))) float f32x4;
typedef __attribute__((ext_vector_type(8))) __bf16 bf16x8;

__device__ __forceinline__ unsigned short f2bf(float f) {
    unsigned int u = __float_as_uint(f);
    u = (u + 0x7FFF + ((u >> 16) & 1)) >> 16;   // RNE
    return (unsigned short)u;
}

// ---------- utility ----------
__global__ void k_zero_int(int* p, int n) {
    int i = blockIdx.x * blockDim.x + threadIdx.x;
    if (i < n) p[i] = 0;
}

// W1t[n][k] = bf16(W1[k][n]), k zero-padded to 512
__global__ void k_prep_w1t(const float* __restrict__ w1, unsigned short* __restrict__ w1t) {
    int idx = blockIdx.x * blockDim.x + threadIdx.x;
    if (idx >= HIDDEN * KPAD) return;
    int n = idx >> 9, k = idx & (KPAD - 1);
    float v = (k < F_IN) ? w1[k * HIDDEN + n] : 0.f;
    w1t[idx] = f2bf(v);
}

// ---------- CSR build: bucketed counting sort ----------
__launch_bounds__(1024)
__global__ void k_bhist(const int* __restrict__ dst, int* __restrict__ bcnt, int e) {
    __shared__ int h[NB];
    for (int i = threadIdx.x; i < NB; i += 1024) h[i] = 0;
    __syncthreads();
    int base = blockIdx.x * EPB;
#pragma unroll
    for (int j = 0; j < 16; ++j) {
        int i = base + j * 1024 + threadIdx.x;
        if (i < e) atomicAdd(&h[dst[i] / NPB], 1);
    }
    __syncthreads();
    for (int i = threadIdx.x; i < NB; i += 1024)
        if (h[i]) atomicAdd(&bcnt[i], h[i]);
}

__launch_bounds__(1024)
__global__ void k_bscan(const int* __restrict__ bcnt, int* __restrict__ bptr,
                        int* __restrict__ bcur) {
    __shared__ int s[1024];
    int t = threadIdx.x;
    int a = bcnt[2 * t], b = bcnt[2 * t + 1];
    int v = a + b;
    s[t] = v;
    __syncthreads();
    for (int off = 1; off < 1024; off <<= 1) {
        int u = (t >= off) ? s[t - off] : 0;
        __syncthreads();
        s[t] += u;
        __syncthreads();
    }
    int excl = s[t] - v;
    bptr[2 * t] = excl;     bptr[2 * t + 1] = excl + a;
    bcur[2 * t] = excl;     bcur[2 * t + 1] = excl + a;
    if (t == 1023) bptr[NB] = s[1023];
}

__launch_bounds__(1024)
__global__ void k_bfill(const int* __restrict__ src, const int* __restrict__ dst,
                        int* __restrict__ bcur, int2* __restrict__ ebuf, int e) {
    __shared__ int hist[NB];
    __shared__ int base_[NB];
    for (int i = threadIdx.x; i < NB; i += 1024) hist[i] = 0;
    __syncthreads();
    int b0 = blockIdx.x * EPB;
    int s_[16], d_[16];
#pragma unroll
    for (int j = 0; j < 16; ++j) {
        int i = b0 + j * 1024 + threadIdx.x;
        if (i < e) {
            s_[j] = src[i];
            d_[j] = dst[i];
            atomicAdd(&hist[d_[j] / NPB], 1);
        } else d_[j] = -1;
    }
    __syncthreads();
    for (int i = threadIdx.x; i < NB; i += 1024) {
        int hc = hist[i];
        base_[i] = hc ? atomicAdd(&bcur[i], hc) : 0;
        hist[i] = 0;    // reuse as local cursor
    }
    __syncthreads();
#pragma unroll
    for (int j = 0; j < 16; ++j) {
        if (d_[j] >= 0) {
            int bu = d_[j] / NPB;
            int r = atomicAdd(&hist[bu], 1);
            ebuf[base_[bu] + r] = make_int2(s_[j], d_[j]);
        }
    }
}

__launch_bounds__(256)
__global__ void k_bucket_csr(const int2* __restrict__ ebuf, const int* __restrict__ bptr,
                             int* __restrict__ rp, int* __restrict__ col,
                             float* __restrict__ dinv, int n) {
    int b  = blockIdx.x;
    int lo = b * NPB;
    if (lo >= n) return;
    int hi  = min(lo + NPB, n);
    int eb0 = bptr[b], ec = bptr[b + 1] - eb0;

    __shared__ int2 pairs[CAP];
    __shared__ int  hist[NPB];
    __shared__ int  excl[NPB + 1];
    for (int j = threadIdx.x; j < NPB; j += 256) hist[j] = 0;
    __syncthreads();
    for (int i = threadIdx.x; i < ec; i += 256) {
        int2 p = ebuf[eb0 + i];
        if (i < CAP) pairs[i] = p;
        atomicAdd(&hist[p.y - lo], 1);
    }
    __syncthreads();
    if (threadIdx.x == 0) {
        int acc = 0;
        for (int j = 0; j < NPB; ++j) { excl[j] = acc; acc += hist[j]; }
        excl[NPB] = acc;
    }
    __syncthreads();
    for (int j = threadIdx.x; j < hi - lo; j += 256) {
        rp[lo + j]   = eb0 + excl[j];
        dinv[lo + j] = rsqrtf((float)(hist[j] + 1));   // +1 self loop
    }
    if (hi == n && threadIdx.x == 0) rp[n] = eb0 + ec;
    __syncthreads();
    for (int j = threadIdx.x; j < NPB; j += 256) hist[j] = 0;  // reuse as cursor
    __syncthreads();
    for (int i = threadIdx.x; i < ec; i += 256) {
        int2 p  = (i < CAP) ? pairs[i] : ebuf[eb0 + i];
        int  li = p.y - lo;
        int  r  = atomicAdd(&hist[li], 1);
        col[eb0 + excl[li] + r] = p.x;
    }
}

// ---------- GEMM1: h[N,64] = x[N,500] @ W1 via bf16 MFMA, LDS-staged A ----------
// block = 256 (4 waves), block tile 128 rows; wave tile 32 rows x 64 cols.
// Per k-tile (K=32): each lane issues 4 independent float4 loads (4KB/wave in
// flight), cvt->bf16, ds_write_b64 into a wave-private LDS slice [32][40]
// (stride 80B: <=2-way banks, free). Fragments via 2x ds_read_b64.
__launch_bounds__(256)
__global__ void k_gemm1(const float* __restrict__ x, const unsigned short* __restrict__ w1t,
                        float* __restrict__ h, int n) {
    __shared__ unsigned short xs[4][32][40];   // 10 KB
    const int tid  = threadIdx.x;
    const int wave = tid >> 6;
    const int lane = tid & 63;
    const int quad = lane >> 4;
    const int l16  = lane & 15;
    const int rowb = blockIdx.x * 128 + wave * 32;

    // staging coords: 4 chunks of 8 rows; lane -> (row = u*8 + lane/8, k = (lane&7)*4)
    const int srow = lane >> 3;
    const int skof = (lane & 7) * 4;

    f32x4 acc[2][4];
#pragma unroll
    for (int rt = 0; rt < 2; ++rt)
#pragma unroll
        for (int ct = 0; ct < 4; ++ct) acc[rt][ct] = (f32x4)0.f;

    for (int ks = 0; ks < 16; ++ks) {
        const int k0 = ks * 32;

        // ---- stage: 4 independent global loads first, then cvt+ds_write ----
        float4 tmp[4];
        if (ks < 15) {
#pragma unroll
            for (int u = 0; u < 4; ++u) {
                int grow = rowb + u * 8 + srow;
                tmp[u] = (grow < n) ? *(const float4*)&x[(size_t)grow * F_IN + k0 + skof]
                                    : make_float4(0.f, 0.f, 0.f, 0.f);
            }
        } else {
#pragma unroll
            for (int u = 0; u < 4; ++u) {
                int grow = rowb + u * 8 + srow;
                const float* p = &x[(size_t)grow * F_IN];
                float v0 = (grow < n && k0 + skof + 0 < F_IN) ? p[k0 + skof + 0] : 0.f;
                float v1 = (grow < n && k0 + skof + 1 < F_IN) ? p[k0 + skof + 1] : 0.f;
                float v2 = (grow < n && k0 + skof + 2 < F_IN) ? p[k0 + skof + 2] : 0.f;
                float v3 = (grow < n && k0 + skof + 3 < F_IN) ? p[k0 + skof + 3] : 0.f;
                tmp[u] = make_float4(v0, v1, v2, v3);
            }
        }
        // B fragments meanwhile (L2-resident w1t)
        bf16x8 bfrag[4];
#pragma unroll
        for (int ct = 0; ct < 4; ++ct)
            bfrag[ct] = *(const bf16x8*)&w1t[(ct * 16 + l16) * KPAD + k0 + quad * 8];

#pragma unroll
        for (int u = 0; u < 4; ++u) {
            unsigned int lo = (unsigned int)f2bf(tmp[u].x) | ((unsigned int)f2bf(tmp[u].y) << 16);
            unsigned int hi = (unsigned int)f2bf(tmp[u].z) | ((unsigned int)f2bf(tmp[u].w) << 16);
            *(uint2*)&xs[wave][u * 8 + srow][skof] = make_uint2(lo, hi);
        }
        __syncthreads();

        // ---- fragments from LDS + MFMA ----
        union { bf16x8 v; unsigned int u[4]; } af[2];
#pragma unroll
        for (int rt = 0; rt < 2; ++rt) {
            uint2 a = *(const uint2*)&xs[wave][rt * 16 + l16][quad * 8];
            uint2 b = *(const uint2*)&xs[wave][rt * 16 + l16][quad * 8 + 4];
            af[rt].u[0] = a.x; af[rt].u[1] = a.y; af[rt].u[2] = b.x; af[rt].u[3] = b.y;
        }
#pragma unroll
        for (int rt = 0; rt < 2; ++rt)
#pragma unroll
            for (int ct = 0; ct < 4; ++ct)
                acc[rt][ct] = __builtin_amdgcn_mfma_f32_16x16x32_bf16(
                    af[rt].v, bfrag[ct], acc[rt][ct], 0, 0, 0);
        __syncthreads();
    }

    // D layout: row = quad*4 + reg, col = lane&15
#pragma unroll
    for (int rt = 0; rt < 2; ++rt) {
#pragma unroll
        for (int reg = 0; reg < 4; ++reg) {
            int grow = rowb + rt * 16 + quad * 4 + reg;
            if (grow < n) {
#pragma unroll
                for (int ct = 0; ct < 4; ++ct)
                    h[(size_t)grow * HIDDEN + ct * 16 + l16] = acc[rt][ct][reg];
            }
        }
    }
}

// ---------- aggregation (+optional ReLU / fused log_softmax) ----------
template <int F, bool RELU, bool LSM>
__global__ void k_agg(const float* __restrict__ h, const int* __restrict__ rp,
                      const int* __restrict__ col, const float* __restrict__ dinv,
                      const float* __restrict__ bias, float* __restrict__ out, int n) {
    int wid  = (blockIdx.x * blockDim.x + threadIdx.x) >> 6;
    int lane = threadIdx.x & 63;
    if (wid >= n) return;
    int beg = rp[wid], end = rp[wid + 1];
    float acc = 0.f;
    int e = beg;
    for (; e + 4 <= end; e += 4) {          // 4-edge unroll -> 4x MLP
        int s0 = col[e], s1 = col[e + 1], s2 = col[e + 2], s3 = col[e + 3];
        float w0 = dinv[s0], w1 = dinv[s1], w2 = dinv[s2], w3 = dinv[s3];
        float h0 = (lane < F) ? h[(size_t)s0 * F + lane] : 0.f;
        float h1 = (lane < F) ? h[(size_t)s1 * F + lane] : 0.f;
        float h2 = (lane < F) ? h[(size_t)s2 * F + lane] : 0.f;
        float h3 = (lane < F) ? h[(size_t)s3 * F + lane] : 0.f;
        acc += w0 * h0 + w1 * h1 + w2 * h2 + w3 * h3;
    }
    for (; e < end; ++e) {
        int s0 = col[e];
        float w0 = dinv[s0];
        float h0 = (lane < F) ? h[(size_t)s0 * F + lane] : 0.f;
        acc += w0 * h0;
    }
    float di    = dinv[wid];
    float selfv = (lane < F) ? h[(size_t)wid * F + lane] : 0.f;
    float r = di * acc + di * di * selfv + ((lane < F) ? bias[lane] : 0.f);
    if (RELU) r = fmaxf(r, 0.f);
    if (LSM) {
        float v = (lane < F) ? r : -INFINITY;
        float m = v;
        for (int off = 32; off; off >>= 1) m = fmaxf(m, __shfl_xor(m, off));
        float ex = (lane < F) ? __expf(v - m) : 0.f;
        float s = ex;
        for (int off = 32; off; off >>= 1) s += __shfl_xor(s, off);
        if (lane < F) out[(size_t)wid * F + lane] = v - m - __logf(s);
    } else {
        if (lane < F) out[(size_t)wid * F + lane] = r;
    }
}

// ---------- GEMM2: h2[N,40] = a[N,64] @ W2[64,40] ----------
__launch_bounds__(256)
__global__ void k_gemm2(const float* __restrict__ a, const float* __restrict__ w,
                        float* __restrict__ out, int n) {
    __shared__ float ws[HIDDEN * N_CLASS];
    for (int idx = threadIdx.x; idx < HIDDEN * N_CLASS; idx += 256) ws[idx] = w[idx];
    __syncthreads();
    int idx = blockIdx.x * 256 + threadIdx.x;
    if (idx >= n * N_CLASS) return;
    int i = idx / N_CLASS, j = idx - i * N_CLASS;
    float s = 0.f;
#pragma unroll
    for (int k = 0; k < HIDDEN; k += 4) {
        float4 xv = *(const float4*)&a[(size_t)i * HIDDEN + k];
        s = fmaf(xv.x, ws[k * N_CLASS + j], s);
        s = fmaf(xv.y, ws[(k + 1) * N_CLASS + j], s);
        s = fmaf(xv.z, ws[(k + 2) * N_CLASS + j], s);
        s = fmaf(xv.w, ws[(k + 3) * N_CLASS + j], s);
    }
    out[idx] = s;
}

extern "C" void kernel_launch(void* const* d_in, const int* in_sizes, int n_in,
                              void* d_out, int out_size, void* d_ws, size_t ws_size,
                              hipStream_t stream) {
    const float* x   = (const float*)d_in[0];
    const float* W1  = (const float*)d_in[1];
    const float* b1  = (const float*)d_in[2];
    const float* W2  = (const float*)d_in[3];
    const float* b2  = (const float*)d_in[4];
    const int*   ei  = (const int*)d_in[5];
    const int*   src = ei;
    const int*   dst = ei + N_EDGES;
    float*       out = (float*)d_out;

    char*  ws  = (char*)d_ws;
    size_t off = 0;
    auto alloc = [&](size_t bytes) -> void* {
        void* p = ws + off;
        off += (bytes + 255) & ~(size_t)255;
        return p;
    };
    int*            bcnt = (int*)alloc((size_t)NB * 4);
    int*            bptr = (int*)alloc((size_t)(NB + 1) * 4);
    int*            bcur = (int*)alloc((size_t)NB * 4);
    int*            rp   = (int*)alloc((size_t)(N_NODES + 1) * 4);
    int*            col  = (int*)alloc((size_t)N_EDGES * 4);
    float*          dinv = (float*)alloc((size_t)N_NODES * 4);
    unsigned short* w1t  = (unsigned short*)alloc((size_t)HIDDEN * KPAD * 2);
    float*          h1   = (float*)alloc((size_t)N_NODES * HIDDEN * 4);
    float*          h1a  = (float*)alloc((size_t)N_NODES * HIDDEN * 4);
    int2*           ebuf = (int2*)h1a;   // alias: ebuf dead before agg1 writes h1a
    float*          h2   = h1;           // h1 dead after agg1

    const int NBH = (N_EDGES + EPB - 1) / EPB;   // 98

    // CSR build (bucketed counting sort) + W1^T prep
    k_zero_int<<<(NB + 255) / 256, 256, 0, stream>>>(bcnt, NB);
    k_prep_w1t<<<(HIDDEN * KPAD + 255) / 256, 256, 0, stream>>>(W1, w1t);
    k_bhist<<<NBH, 1024, 0, stream>>>(dst, bcnt, N_EDGES);
    k_bscan<<<1, 1024, 0, stream>>>(bcnt, bptr, bcur);
    k_bfill<<<NBH, 1024, 0, stream>>>(src, dst, bcur, ebuf, N_EDGES);
    k_bucket_csr<<<NB, 256, 0, stream>>>(ebuf, bptr, rp, col, dinv, N_NODES);

    // layer 1
    k_gemm1<<<(N_NODES + 127) / 128, 256, 0, stream>>>(x, w1t, h1, N_NODES);
    k_agg<HIDDEN, true, false><<<(N_NODES + 3) / 4, 256, 0, stream>>>(h1, rp, col, dinv, b1, h1a, N_NODES);

    // layer 2 (+fused log_softmax)
    k_gemm2<<<(N_NODES * N_CLASS + 255) / 256, 256, 0, stream>>>(h1a, W2, h2, N_NODES);
    k_agg<N_CLASS, false, true><<<(N_NODES + 3) / 4, 256, 0, stream>>>(h2, rp, col, dinv, b2, out, N_NODES);
}